// Round 1
// baseline (185.919 us; speedup 1.0000x reference)
//
#include <hip/hip_runtime.h>

// ---------------- problem constants ----------------
constexpr int S    = 8192;
constexpr int D    = 768;
constexpr int NMID = 10;
constexpr int EPH  = 820;   // edges_per_high = ceil(8192/10)

// ---------------- workspace layout (floats) ----------------
constexpr int OFF_MADJ = 0;                   // 100   mid_adj (atomic)
constexpr int OFF_MID  = 128;                 // 7680  mid = m1^T x (atomic)
constexpr int OFF_MATT = OFF_MID  + 7680;     // 7680  mid @ att_low_mid (atomic)
constexpr int OFF_Y1   = OFF_MATT + 7680;     // 7680  midrep @ W1 (atomic)
constexpr int OFF_Z2   = OFF_Y1   + 7680;     // 3840  mid2 @ att_mid_high (atomic)
constexpr int OFF_Y2   = OFF_Z2   + 3840;     // 3840  out2 @ W2 (atomic)
constexpr int ZERO_END = OFF_Y2   + 3840;     // 30848 -- everything below is zero-init'd
constexpr int OFF_MREP = ZERO_END;            // 7680  mid_rep (init=mid, then += P@x)
constexpr int OFF_SC   = OFF_MREP + 7680;     // 81920 scores transposed [8192][10]
constexpr int OFF_XMID = OFF_SC   + 81920;    // 7680
constexpr int OFF_MID2 = OFF_XMID + 7680;     // 3840
constexpr int OFF_OUT2 = OFF_MID2 + 3840;     // 3840
constexpr int OFF_NM   = OFF_OUT2 + 3840;     // 100   normalized mid adjacency
constexpr int OFF_NH   = OFF_NM   + 100;      // 25    normalized high adjacency

// ---------------- kernels ----------------

__global__ __launch_bounds__(256) void k_zero(float* ws) {
    for (int i = blockIdx.x * 256 + threadIdx.x; i < ZERO_END; i += 32 * 256)
        ws[i] = 0.f;
}

// blocks [0,800): adjacency 10x10 cluster block sums (split 8-way over rows)
// blocks [800,1280): mid = m1^T @ x  (10 clusters x 3 col-chunks x 16 row-splits)
__global__ __launch_bounds__(256) void k_bigpass(const float* __restrict__ A,
                                                 const float* __restrict__ x,
                                                 float* __restrict__ ws) {
    __shared__ float red[256];
    int bx = blockIdx.x;
    if (bx < 800) {
        int p = bx >> 3, sp = bx & 7;
        int i = p / 10, j = p % 10;
        int r0 = i * EPH, r1 = min(r0 + EPH, S);
        int c0 = j * EPH, c1 = min(c0 + EPH, S);
        int nr = r1 - r0;
        int rs0 = r0 + (nr * sp) / 8, rs1 = r0 + (nr * (sp + 1)) / 8;
        int nc4 = (c1 - c0) >> 2;
        float acc = 0.f;
        for (int r = rs0; r < rs1; ++r) {
            const float4* row = (const float4*)(A + (size_t)r * S + c0);
            for (int t = threadIdx.x; t < nc4; t += 256) {
                float4 v = row[t];
                acc += (v.x + v.y) + (v.z + v.w);
            }
        }
        red[threadIdx.x] = acc;
        __syncthreads();
        for (int off = 128; off > 0; off >>= 1) {
            if (threadIdx.x < off) red[threadIdx.x] += red[threadIdx.x + off];
            __syncthreads();
        }
        if (threadIdx.x == 0) atomicAdd(&ws[OFF_MADJ + i * 10 + j], red[0]);
    } else {
        int b  = bx - 800;
        int cl = b / 48;
        int rem = b % 48;
        int cc = rem / 16, sp = rem % 16;
        int r0 = cl * EPH, r1 = min(r0 + EPH, S);
        int nr = r1 - r0;
        int rs0 = r0 + (nr * sp) / 16, rs1 = r0 + (nr * (sp + 1)) / 16;
        int c = cc * 256 + threadIdx.x;
        float acc = 0.f;
        for (int r = rs0; r < rs1; ++r) acc += x[(size_t)r * D + c];
        atomicAdd(&ws[OFF_MID + cl * D + c], acc);
    }
}

// midrep = mid (copy before PV accumulation)
__global__ __launch_bounds__(256) void k_copy(float* ws) {
    for (int i = blockIdx.x * 256 + threadIdx.x; i < NMID * D; i += 8 * 256)
        ws[OFF_MREP + i] = ws[OFF_MID + i];
}

// out[NR][768] += in[NR][768] @ W[768][768], k-split over 48 blocks (chunk=16)
template <int NR>
__global__ __launch_bounds__(256) void k_mm(const float* __restrict__ W,
                                            const float* __restrict__ in,
                                            float* __restrict__ out) {
    __shared__ float mi[NR * 16];
    int kb = blockIdx.x * 16;
    for (int t = threadIdx.x; t < NR * 16; t += 256)
        mi[t] = in[(t >> 4) * D + kb + (t & 15)];
    __syncthreads();
    int c = threadIdx.x;
    float a0[NR], a1[NR], a2[NR];
#pragma unroll
    for (int i = 0; i < NR; ++i) { a0[i] = 0.f; a1[i] = 0.f; a2[i] = 0.f; }
    for (int kk = 0; kk < 16; ++kk) {
        const float* wr = W + (size_t)(kb + kk) * D;
        float w0 = wr[c], w1 = wr[c + 256], w2 = wr[c + 512];
#pragma unroll
        for (int i = 0; i < NR; ++i) {
            float m = mi[i * 16 + kk];
            a0[i] += m * w0; a1[i] += m * w1; a2[i] += m * w2;
        }
    }
#pragma unroll
    for (int i = 0; i < NR; ++i) {
        atomicAdd(&out[i * D + c],       a0[i]);
        atomicAdd(&out[i * D + c + 256], a1[i]);
        atomicAdd(&out[i * D + c + 512], a2[i]);
    }
}

// scores^T[r][i] = (rc(r)==i) ? 0 : dot(midatt[i], x[r]); 256 blocks x 32 rows
__global__ __launch_bounds__(256) void k_scores(const float* __restrict__ x,
                                                float* __restrict__ ws) {
    __shared__ float ma[NMID * D];   // 30 KB
    for (int t = threadIdx.x; t < NMID * D; t += 256) ma[t] = ws[OFF_MATT + t];
    __syncthreads();
    const float4* maf = (const float4*)ma;
    const float4* x4  = (const float4*)x;
    int wave = threadIdx.x >> 6, ln = threadIdx.x & 63;
    int rbase = blockIdx.x * 32 + wave * 8;
    for (int rr = 0; rr < 8; ++rr) {
        int r = rbase + rr;
        float4 v0 = x4[(size_t)r * 192 + ln];
        float4 v1 = x4[(size_t)r * 192 + 64 + ln];
        float4 v2 = x4[(size_t)r * 192 + 128 + ln];
        int rc = r / EPH;
#pragma unroll
        for (int i = 0; i < NMID; ++i) {
            float4 m0 = maf[i * 192 + ln];
            float4 m1 = maf[i * 192 + 64 + ln];
            float4 m2 = maf[i * 192 + 128 + ln];
            float p = m0.x * v0.x + m0.y * v0.y + m0.z * v0.z + m0.w * v0.w
                    + m1.x * v1.x + m1.y * v1.y + m1.z * v1.z + m1.w * v1.w
                    + m2.x * v2.x + m2.y * v2.y + m2.z * v2.z + m2.w * v2.w;
#pragma unroll
            for (int off = 32; off > 0; off >>= 1) p += __shfl_down(p, off, 64);
            if (ln == 0) ws[OFF_SC + r * NMID + i] = (rc == i) ? 0.f : p;
        }
    }
}

// blocks 0..9: softmax over row i of scores^T; block 10: GCN normalizations
__global__ __launch_bounds__(256) void k_softmax(float* __restrict__ ws) {
    __shared__ float red[256];
    int i = blockIdx.x;
    if (i < NMID) {
        int tid = threadIdx.x;
        float m = -1e30f;
        for (int r = tid; r < S; r += 256) m = fmaxf(m, ws[OFF_SC + r * NMID + i]);
        red[tid] = m; __syncthreads();
        for (int off = 128; off > 0; off >>= 1) {
            if (tid < off) red[tid] = fmaxf(red[tid], red[tid + off]);
            __syncthreads();
        }
        float M = red[0]; __syncthreads();
        float s = 0.f;
        for (int r = tid; r < S; r += 256) s += expf(ws[OFF_SC + r * NMID + i] - M);
        red[tid] = s; __syncthreads();
        for (int off = 128; off > 0; off >>= 1) {
            if (tid < off) red[tid] += red[tid + off];
            __syncthreads();
        }
        float inv = 1.f / red[0]; __syncthreads();
        for (int r = tid; r < S; r += 256) {
            int idx = OFF_SC + r * NMID + i;
            ws[idx] = expf(ws[idx] - M) * inv;
        }
    } else if (threadIdx.x == 0) {
        float aa[100];
#pragma unroll
        for (int t = 0; t < 100; ++t) aa[t] = ws[OFF_MADJ + t];
        float dg[10];
#pragma unroll
        for (int r = 0; r < 10; ++r) {
            float sum = 0.f;
#pragma unroll
            for (int j = 0; j < 10; ++j) sum += (r == j) ? 1.0f : aa[r * 10 + j];
            dg[r] = 1.0f / sqrtf(fmaxf(sum, 1.0f));
        }
#pragma unroll
        for (int r = 0; r < 10; ++r)
#pragma unroll
            for (int j = 0; j < 10; ++j)
                ws[OFF_NM + r * 10 + j] = dg[r] * ((r == j) ? 1.0f : aa[r * 10 + j]) * dg[j];
        float ha[25];
#pragma unroll
        for (int a = 0; a < 5; ++a)
#pragma unroll
            for (int b = 0; b < 5; ++b)
                ha[a * 5 + b] = aa[(2 * a) * 10 + 2 * b] + aa[(2 * a) * 10 + 2 * b + 1]
                              + aa[(2 * a + 1) * 10 + 2 * b] + aa[(2 * a + 1) * 10 + 2 * b + 1];
        float dh[5];
#pragma unroll
        for (int r = 0; r < 5; ++r) {
            float sum = 0.f;
#pragma unroll
            for (int j = 0; j < 5; ++j) sum += (r == j) ? 1.0f : ha[r * 5 + j];
            dh[r] = 1.0f / sqrtf(fmaxf(sum, 1.0f));
        }
#pragma unroll
        for (int r = 0; r < 5; ++r)
#pragma unroll
            for (int j = 0; j < 5; ++j)
                ws[OFF_NH + r * 5 + j] = dh[r] * ((r == j) ? 1.0f : ha[r * 5 + j]) * dh[j];
    }
}

// mid_rep += P @ x ; 128 blocks x 64 rows, 192 threads each own a float4 column group
__global__ __launch_bounds__(192) void k_pv(const float* __restrict__ x,
                                            float* __restrict__ ws) {
    __shared__ float p[64 * NMID];
    int r0 = blockIdx.x * 64;
    int tid = threadIdx.x;
    for (int t = tid; t < 64 * NMID; t += 192) p[t] = ws[OFF_SC + r0 * NMID + t];
    __syncthreads();
    const float4* x4 = (const float4*)x;
    float4 acc[NMID];
#pragma unroll
    for (int i = 0; i < NMID; ++i) acc[i] = make_float4(0.f, 0.f, 0.f, 0.f);
    for (int r = 0; r < 64; ++r) {
        float4 xv = x4[(size_t)(r0 + r) * 192 + tid];
#pragma unroll
        for (int i = 0; i < NMID; ++i) {
            float pv = p[r * NMID + i];
            acc[i].x += pv * xv.x; acc[i].y += pv * xv.y;
            acc[i].z += pv * xv.z; acc[i].w += pv * xv.w;
        }
    }
#pragma unroll
    for (int i = 0; i < NMID; ++i) {
        float* base = ws + OFF_MREP + i * D + tid * 4;
        atomicAdd(base + 0, acc[i].x);
        atomicAdd(base + 1, acc[i].y);
        atomicAdd(base + 2, acc[i].z);
        atomicAdd(base + 3, acc[i].w);
    }
}

// x_mid = relu(norm_mid @ y1 + b1); mid2 = pair sums
__global__ __launch_bounds__(768) void k_xmid(const float* __restrict__ b1,
                                              float* __restrict__ ws) {
    __shared__ float nm[100];
    for (int t = threadIdx.x; t < 100; t += 768) nm[t] = ws[OFF_NM + t];
    __syncthreads();
    int c = threadIdx.x;
    float yv[10];
#pragma unroll
    for (int j = 0; j < 10; ++j) yv[j] = ws[OFF_Y1 + j * D + c];
    float bias = b1[c];
    float xm[10];
#pragma unroll
    for (int i = 0; i < 10; ++i) {
        float s = bias;
#pragma unroll
        for (int j = 0; j < 10; ++j) s += nm[i * 10 + j] * yv[j];
        xm[i] = fmaxf(s, 0.f);
        ws[OFF_XMID + i * D + c] = xm[i];
    }
#pragma unroll
    for (int a = 0; a < 5; ++a)
        ws[OFF_MID2 + a * D + c] = xm[2 * a] + xm[2 * a + 1];
}

// level-2 attention: scores2 = z2 @ xmid^T (masked, softmax over 10), out2 = P2@xmid + mid2
__global__ __launch_bounds__(768) void k_attn2(float* __restrict__ ws) {
    __shared__ float s2[64];
    int tid = threadIdx.x;
    int wv = tid >> 6, ln = tid & 63;
    for (int p = wv; p < 50; p += 12) {
        int i = p / 10, r = p % 10;
        const float4* za = (const float4*)(ws + OFF_Z2 + i * D);
        const float4* xa = (const float4*)(ws + OFF_XMID + r * D);
        float acc = 0.f;
#pragma unroll
        for (int q = 0; q < 3; ++q) {
            float4 a = za[q * 64 + ln], b = xa[q * 64 + ln];
            acc += a.x * b.x + a.y * b.y + a.z * b.z + a.w * b.w;
        }
#pragma unroll
        for (int off = 32; off > 0; off >>= 1) acc += __shfl_down(acc, off, 64);
        if (ln == 0) s2[p] = ((r >> 1) == i) ? 0.f : acc;
    }
    __syncthreads();
    if (tid < 5) {
        float mx = -1e30f;
#pragma unroll
        for (int r = 0; r < 10; ++r) mx = fmaxf(mx, s2[tid * 10 + r]);
        float sm = 0.f; float e[10];
#pragma unroll
        for (int r = 0; r < 10; ++r) { e[r] = expf(s2[tid * 10 + r] - mx); sm += e[r]; }
#pragma unroll
        for (int r = 0; r < 10; ++r) s2[tid * 10 + r] = e[r] / sm;
    }
    __syncthreads();
    int c = tid;
    float o[5];
#pragma unroll
    for (int i = 0; i < 5; ++i) o[i] = ws[OFF_MID2 + i * D + c];
#pragma unroll
    for (int r = 0; r < 10; ++r) {
        float xv = ws[OFF_XMID + r * D + c];
#pragma unroll
        for (int i = 0; i < 5; ++i) o[i] += s2[i * 10 + r] * xv;
    }
#pragma unroll
    for (int i = 0; i < 5; ++i) ws[OFF_OUT2 + i * D + c] = o[i];
}

// out = mean_i relu(norm_high @ y2 + b2)
__global__ __launch_bounds__(768) void k_final(const float* __restrict__ b2,
                                               const float* __restrict__ ws,
                                               float* __restrict__ out) {
    __shared__ float nh[25];
    for (int t = threadIdx.x; t < 25; t += 768) nh[t] = ws[OFF_NH + t];
    __syncthreads();
    int c = threadIdx.x;
    float y[5];
#pragma unroll
    for (int j = 0; j < 5; ++j) y[j] = ws[OFF_Y2 + j * D + c];
    float bias = b2[c];
    float s = 0.f;
#pragma unroll
    for (int i = 0; i < 5; ++i) {
        float v = bias;
#pragma unroll
        for (int j = 0; j < 5; ++j) v += nh[i * 5 + j] * y[j];
        s += fmaxf(v, 0.f);
    }
    out[c] = s * 0.2f;
}

// ---------------- launcher ----------------
extern "C" void kernel_launch(void* const* d_in, const int* in_sizes, int n_in,
                              void* d_out, int out_size, void* d_ws, size_t ws_size,
                              hipStream_t stream) {
    const float* x    = (const float*)d_in[0];
    const float* adj  = (const float*)d_in[1];
    const float* attL = (const float*)d_in[2];
    const float* W1   = (const float*)d_in[3];
    const float* b1   = (const float*)d_in[4];
    const float* attH = (const float*)d_in[5];
    const float* W2   = (const float*)d_in[6];
    const float* b2   = (const float*)d_in[7];
    float* ws  = (float*)d_ws;
    float* out = (float*)d_out;

    k_zero   <<<32,   256, 0, stream>>>(ws);
    k_bigpass<<<1280, 256, 0, stream>>>(adj, x, ws);
    k_copy   <<<8,    256, 0, stream>>>(ws);
    k_mm<10> <<<48,   256, 0, stream>>>(attL, ws + OFF_MID,  ws + OFF_MATT);
    k_scores <<<256,  256, 0, stream>>>(x, ws);
    k_softmax<<<11,   256, 0, stream>>>(ws);
    k_pv     <<<128,  192, 0, stream>>>(x, ws);
    k_mm<10> <<<48,   256, 0, stream>>>(W1, ws + OFF_MREP, ws + OFF_Y1);
    k_xmid   <<<1,    768, 0, stream>>>(b1, ws);
    k_mm<5>  <<<48,   256, 0, stream>>>(attH, ws + OFF_MID2, ws + OFF_Z2);
    k_attn2  <<<1,    768, 0, stream>>>(ws);
    k_mm<5>  <<<48,   256, 0, stream>>>(W2, ws + OFF_OUT2, ws + OFF_Y2);
    k_final  <<<1,    768, 0, stream>>>(b2, ws, out);
}

// Round 2
// 165.933 us; speedup vs baseline: 1.1204x; 1.1204x over previous
//
#include <hip/hip_runtime.h>

// ---------------- problem constants ----------------
constexpr int S    = 8192;
constexpr int D    = 768;
constexpr int NMID = 10;
constexpr int EPH  = 820;   // edges_per_high = ceil(8192/10)

// ---------------- workspace layout (float element offsets) ----------------
constexpr int PART_ADJ = 0;        // 800   per-(pair,rowsplit) adjacency partial sums
constexpr int PART_MID = 1024;     // 16*10*768 = 122880 mid partials [sp][cl][col]
constexpr int OFF_ZB   = 123904;   // zero-init base (5 atomic-target buffers)
constexpr int OFF_MATT = 123904;   // 7680  mid @ att_low_mid (atomic)
constexpr int OFF_MREP = 131584;   // 7680  P @ x (atomic)
constexpr int OFF_Y1   = 139264;   // 7680  (mid+mrep) @ W1 (atomic)
constexpr int OFF_Z2   = 146944;   // 3840  mid2 @ att_mid_high (atomic)
constexpr int OFF_Y2   = 150784;   // 3840  out2 @ W2 (atomic)
constexpr int ZERO_N   = 30720;    // ends at 154624
constexpr int OFF_MID  = 154624;   // 7680  reduced mid = m1^T x
constexpr int OFF_XMID = 162304;   // 7680
constexpr int OFF_SC   = 169984;   // 81920 raw masked scores [8192][10]
constexpr int OFF_SCB  = 251904;   // 256*10*2 per-block softmax stats (m, sumexp)

// ---------------- shared mm core: out[NR][768] += mi[NR][16] @ W[kb:kb+16][768]
template <int NR>
__device__ __forceinline__ void mm_core(const float* __restrict__ W,
                                        const float* mi,      // LDS [NR*16]
                                        float* __restrict__ out, int kb) {
    int c = threadIdx.x;
    float a0[NR], a1[NR], a2[NR];
#pragma unroll
    for (int i = 0; i < NR; ++i) { a0[i] = 0.f; a1[i] = 0.f; a2[i] = 0.f; }
    for (int kk = 0; kk < 16; ++kk) {
        const float* wr = W + (size_t)(kb + kk) * D;
        float w0 = wr[c], w1 = wr[c + 256], w2 = wr[c + 512];
#pragma unroll
        for (int i = 0; i < NR; ++i) {
            float m = mi[i * 16 + kk];
            a0[i] += m * w0; a1[i] += m * w1; a2[i] += m * w2;
        }
    }
#pragma unroll
    for (int i = 0; i < NR; ++i) {
        atomicAdd(&out[i * D + c],       a0[i]);
        atomicAdd(&out[i * D + c + 256], a1[i]);
        atomicAdd(&out[i * D + c + 512], a2[i]);
    }
}

// ---------------- kernel 1: big HBM pass ----------------
// blocks [0,800): adjacency partial sums -> PART_ADJ[bx]
// blocks [800,1280): mid col-sum partials -> PART_MID
// blocks [1280,1296): zero the atomic-target buffers
__global__ __launch_bounds__(256) void k_big(const float* __restrict__ A,
                                             const float* __restrict__ x,
                                             float* __restrict__ ws) {
    int bx = blockIdx.x;
    int tid = threadIdx.x;
    if (bx < 800) {
        __shared__ float red[256];
        int p = bx >> 3, sp = bx & 7;
        int i = p / 10, j = p % 10;
        int r0 = i * EPH, r1 = min(r0 + EPH, S);
        int c0 = j * EPH, c1 = min(c0 + EPH, S);
        int nr = r1 - r0;
        int rs0 = r0 + (nr * sp) / 8, rs1 = r0 + (nr * (sp + 1)) / 8;
        int nc4 = (c1 - c0) >> 2;
        float acc = 0.f;
        for (int r = rs0; r < rs1; ++r) {
            const float4* row = (const float4*)(A + (size_t)r * S + c0);
            for (int t = tid; t < nc4; t += 256) {
                float4 v = row[t];
                acc += (v.x + v.y) + (v.z + v.w);
            }
        }
        red[tid] = acc;
        __syncthreads();
        for (int off = 128; off > 0; off >>= 1) {
            if (tid < off) red[tid] += red[tid + off];
            __syncthreads();
        }
        if (tid == 0) ws[PART_ADJ + bx] = red[0];
    } else if (bx < 1280) {
        int b  = bx - 800;
        int cl = b / 48;
        int rem = b % 48;
        int cc = rem / 16, sp = rem % 16;
        int r0 = cl * EPH, r1 = min(r0 + EPH, S);
        int nr = r1 - r0;
        int rs0 = r0 + (nr * sp) / 16, rs1 = r0 + (nr * (sp + 1)) / 16;
        int c = cc * 256 + tid;
        float acc = 0.f;
        for (int r = rs0; r < rs1; ++r) acc += x[(size_t)r * D + c];
        ws[PART_MID + (sp * NMID + cl) * D + c] = acc;
    } else {
        int b = bx - 1280;
        for (int t = b * 256 + tid; t < ZERO_N; t += 16 * 256)
            ws[OFF_ZB + t] = 0.f;
    }
}

// ---------------- kernel 2: reduce mid slice + mid @ attL ----------------
__global__ __launch_bounds__(256) void k_mmA(const float* __restrict__ attL,
                                             float* __restrict__ ws) {
    __shared__ float mi[160];
    int kb = blockIdx.x * 16;
    int tid = threadIdx.x;
    if (tid < 160) {
        int cl = tid >> 4, k = tid & 15;
        float s = 0.f;
#pragma unroll
        for (int sp = 0; sp < 16; ++sp)
            s += ws[PART_MID + (sp * NMID + cl) * D + kb + k];
        mi[tid] = s;
        ws[OFF_MID + cl * D + kb + k] = s;
    }
    __syncthreads();
    mm_core<10>(attL, mi, ws + OFF_MATT, kb);
}

// ---------------- kernel 3: scores + per-block softmax stats ----------------
__global__ __launch_bounds__(256) void k_scores(const float* __restrict__ x,
                                                float* __restrict__ ws) {
    __shared__ float ma[NMID * D];   // 30 KB
    __shared__ float scl[32 * NMID];
    int tid = threadIdx.x;
    for (int t = tid; t < NMID * D; t += 256) ma[t] = ws[OFF_MATT + t];
    __syncthreads();
    const float4* maf = (const float4*)ma;
    const float4* x4  = (const float4*)x;
    int wave = tid >> 6, ln = tid & 63;
    int rbase = blockIdx.x * 32 + wave * 8;
    for (int rr = 0; rr < 8; ++rr) {
        int r = rbase + rr;
        float4 v0 = x4[(size_t)r * 192 + ln];
        float4 v1 = x4[(size_t)r * 192 + 64 + ln];
        float4 v2 = x4[(size_t)r * 192 + 128 + ln];
        int rc = r / EPH;
#pragma unroll
        for (int i = 0; i < NMID; ++i) {
            float4 m0 = maf[i * 192 + ln];
            float4 m1 = maf[i * 192 + 64 + ln];
            float4 m2 = maf[i * 192 + 128 + ln];
            float p = m0.x * v0.x + m0.y * v0.y + m0.z * v0.z + m0.w * v0.w
                    + m1.x * v1.x + m1.y * v1.y + m1.z * v1.z + m1.w * v1.w
                    + m2.x * v2.x + m2.y * v2.y + m2.z * v2.z + m2.w * v2.w;
#pragma unroll
            for (int off = 32; off > 0; off >>= 1) p += __shfl_down(p, off, 64);
            if (ln == 0) {
                float v = (rc == i) ? 0.f : p;
                ws[OFF_SC + r * NMID + i] = v;
                scl[(wave * 8 + rr) * NMID + i] = v;
            }
        }
    }
    __syncthreads();
    if (tid < NMID) {
        float m = -1e30f;
        for (int r = 0; r < 32; ++r) m = fmaxf(m, scl[r * NMID + tid]);
        float s = 0.f;
        for (int r = 0; r < 32; ++r) s += expf(scl[r * NMID + tid] - m);
        ws[OFF_SCB + blockIdx.x * 20 + tid * 2]     = m;
        ws[OFF_SCB + blockIdx.x * 20 + tid * 2 + 1] = s;
    }
}

// ---------------- kernel 4: softmax finalize + P @ x -> MREP ----------------
__global__ __launch_bounds__(192) void k_pv(const float* __restrict__ x,
                                            float* __restrict__ ws) {
    __shared__ float lm[160], ls[160], Mi[10], Inv[10], p[64 * NMID];
    int tid = threadIdx.x;
    if (tid < 160) {
        int i = tid >> 4, seg = tid & 15;
        float m = -1e30f;
        for (int b = seg * 16; b < seg * 16 + 16; ++b)
            m = fmaxf(m, ws[OFF_SCB + b * 20 + i * 2]);
        float s = 0.f;
        for (int b = seg * 16; b < seg * 16 + 16; ++b)
            s += ws[OFF_SCB + b * 20 + i * 2 + 1] *
                 expf(ws[OFF_SCB + b * 20 + i * 2] - m);
        lm[tid] = m; ls[tid] = s;
    }
    __syncthreads();
    if (tid < NMID) {
        float M = -1e30f;
        for (int g = 0; g < 16; ++g) M = fmaxf(M, lm[tid * 16 + g]);
        float Ssum = 0.f;
        for (int g = 0; g < 16; ++g) Ssum += ls[tid * 16 + g] * expf(lm[tid * 16 + g] - M);
        Mi[tid] = M; Inv[tid] = 1.f / Ssum;
    }
    __syncthreads();
    int r0 = blockIdx.x * 64;
    for (int t = tid; t < 64 * NMID; t += 192) {
        int i = t % NMID;
        p[t] = expf(ws[OFF_SC + r0 * NMID + t] - Mi[i]) * Inv[i];
    }
    __syncthreads();
    const float4* x4 = (const float4*)x;
    float4 acc[NMID];
#pragma unroll
    for (int i = 0; i < NMID; ++i) acc[i] = make_float4(0.f, 0.f, 0.f, 0.f);
    for (int r = 0; r < 64; ++r) {
        float4 xv = x4[(size_t)(r0 + r) * 192 + tid];
#pragma unroll
        for (int i = 0; i < NMID; ++i) {
            float pv = p[r * NMID + i];
            acc[i].x += pv * xv.x; acc[i].y += pv * xv.y;
            acc[i].z += pv * xv.z; acc[i].w += pv * xv.w;
        }
    }
#pragma unroll
    for (int i = 0; i < NMID; ++i) {
        float* base = ws + OFF_MREP + i * D + tid * 4;
        atomicAdd(base + 0, acc[i].x);
        atomicAdd(base + 1, acc[i].y);
        atomicAdd(base + 2, acc[i].z);
        atomicAdd(base + 3, acc[i].w);
    }
}

// ---------------- kernel 5: (mid + mrep) @ W1 -> Y1 ----------------
__global__ __launch_bounds__(256) void k_mmB(const float* __restrict__ W1,
                                             float* __restrict__ ws) {
    __shared__ float mi[160];
    int kb = blockIdx.x * 16;
    int tid = threadIdx.x;
    if (tid < 160) {
        int cl = tid >> 4, k = tid & 15;
        mi[tid] = ws[OFF_MID + cl * D + kb + k] + ws[OFF_MREP + cl * D + kb + k];
    }
    __syncthreads();
    mm_core<10>(W1, mi, ws + OFF_Y1, kb);
}

// ---------------- kernel 6: NM; x_mid slice; mid2 @ attH -> Z2 ----------------
__global__ __launch_bounds__(256) void k_mmC(const float* __restrict__ attH,
                                             const float* __restrict__ b1,
                                             float* __restrict__ ws) {
    __shared__ float aa[100], dg[10], NM[100], xml[160], mi[80];
    int tid = threadIdx.x;
    if (tid < 100) {
        float s = 0.f;
#pragma unroll
        for (int sp = 0; sp < 8; ++sp) s += ws[PART_ADJ + tid * 8 + sp];
        aa[tid] = s;
    }
    __syncthreads();
    if (tid < 10) {
        float s = 0.f;
#pragma unroll
        for (int j = 0; j < 10; ++j) s += (tid == j) ? 1.0f : aa[tid * 10 + j];
        dg[tid] = 1.0f / sqrtf(fmaxf(s, 1.0f));
    }
    __syncthreads();
    if (tid < 100) {
        int i = tid / 10, j = tid % 10;
        NM[tid] = dg[i] * ((i == j) ? 1.0f : aa[tid]) * dg[j];
    }
    __syncthreads();
    int kb = blockIdx.x * 16;
    if (tid < 160) {
        int i = tid >> 4, c = kb + (tid & 15);
        float s = b1[c];
#pragma unroll
        for (int j = 0; j < 10; ++j) s += NM[i * 10 + j] * ws[OFF_Y1 + j * D + c];
        float xm = fmaxf(s, 0.f);
        ws[OFF_XMID + i * D + c] = xm;
        xml[tid] = xm;
    }
    __syncthreads();
    if (tid < 80) {
        int a = tid >> 4, k = tid & 15;
        mi[tid] = xml[(2 * a) * 16 + k] + xml[(2 * a + 1) * 16 + k];
    }
    __syncthreads();
    mm_core<5>(attH, mi, ws + OFF_Z2, kb);
}

// ---------------- kernel 7: level-2 attention + out2 @ W2 -> Y2 ----------------
__global__ __launch_bounds__(256) void k_mmD(const float* __restrict__ W2,
                                             float* __restrict__ ws) {
    __shared__ float s2[64], P2[50], mi[80];
    int tid = threadIdx.x, wv = tid >> 6, ln = tid & 63;
    for (int pp = wv; pp < 50; pp += 4) {
        int i = pp / 10, r = pp % 10;
        const float4* za = (const float4*)(ws + OFF_Z2 + i * D);
        const float4* xa = (const float4*)(ws + OFF_XMID + r * D);
        float acc = 0.f;
#pragma unroll
        for (int q = 0; q < 3; ++q) {
            float4 a = za[q * 64 + ln], b = xa[q * 64 + ln];
            acc += a.x * b.x + a.y * b.y + a.z * b.z + a.w * b.w;
        }
#pragma unroll
        for (int off = 32; off > 0; off >>= 1) acc += __shfl_down(acc, off, 64);
        if (ln == 0) s2[pp] = ((r >> 1) == i) ? 0.f : acc;
    }
    __syncthreads();
    if (tid < 5) {
        float mx = -1e30f;
#pragma unroll
        for (int r = 0; r < 10; ++r) mx = fmaxf(mx, s2[tid * 10 + r]);
        float sm = 0.f; float e[10];
#pragma unroll
        for (int r = 0; r < 10; ++r) { e[r] = expf(s2[tid * 10 + r] - mx); sm += e[r]; }
#pragma unroll
        for (int r = 0; r < 10; ++r) P2[tid * 10 + r] = e[r] / sm;
    }
    __syncthreads();
    int kb = blockIdx.x * 16;
    if (tid < 80) {
        int i = tid >> 4, c = kb + (tid & 15);
        float xm[10];
#pragma unroll
        for (int r = 0; r < 10; ++r) xm[r] = ws[OFF_XMID + r * D + c];
        float o = xm[2 * i] + xm[2 * i + 1];
#pragma unroll
        for (int r = 0; r < 10; ++r) o += P2[i * 10 + r] * xm[r];
        mi[tid] = o;
    }
    __syncthreads();
    mm_core<5>(W2, mi, ws + OFF_Y2, kb);
}

// ---------------- kernel 8: NH; out = mean relu(NH @ Y2 + b2) ----------------
__global__ __launch_bounds__(768) void k_final(const float* __restrict__ b2,
                                               const float* __restrict__ ws,
                                               float* __restrict__ out) {
    __shared__ float aa[100], ha[25], dh[5], NH[25];
    int tid = threadIdx.x;
    if (tid < 100) {
        float s = 0.f;
#pragma unroll
        for (int sp = 0; sp < 8; ++sp) s += ws[PART_ADJ + tid * 8 + sp];
        aa[tid] = s;
    }
    __syncthreads();
    if (tid < 25) {
        int a = tid / 5, b = tid % 5;
        ha[tid] = aa[(2 * a) * 10 + 2 * b] + aa[(2 * a) * 10 + 2 * b + 1]
                + aa[(2 * a + 1) * 10 + 2 * b] + aa[(2 * a + 1) * 10 + 2 * b + 1];
    }
    __syncthreads();
    if (tid < 5) {
        float s = 0.f;
#pragma unroll
        for (int j = 0; j < 5; ++j) s += (tid == j) ? 1.0f : ha[tid * 5 + j];
        dh[tid] = 1.0f / sqrtf(fmaxf(s, 1.0f));
    }
    __syncthreads();
    if (tid < 25) {
        int i = tid / 5, j = tid % 5;
        NH[tid] = dh[i] * ((i == j) ? 1.0f : ha[tid]) * dh[j];
    }
    __syncthreads();
    int c = tid;
    float y[5];
#pragma unroll
    for (int j = 0; j < 5; ++j) y[j] = ws[OFF_Y2 + j * D + c];
    float bias = b2[c];
    float s = 0.f;
#pragma unroll
    for (int i = 0; i < 5; ++i) {
        float v = bias;
#pragma unroll
        for (int j = 0; j < 5; ++j) v += NH[i * 5 + j] * y[j];
        s += fmaxf(v, 0.f);
    }
    out[c] = s * 0.2f;
}

// ---------------- launcher ----------------
extern "C" void kernel_launch(void* const* d_in, const int* in_sizes, int n_in,
                              void* d_out, int out_size, void* d_ws, size_t ws_size,
                              hipStream_t stream) {
    const float* x    = (const float*)d_in[0];
    const float* adj  = (const float*)d_in[1];
    const float* attL = (const float*)d_in[2];
    const float* W1   = (const float*)d_in[3];
    const float* b1   = (const float*)d_in[4];
    const float* attH = (const float*)d_in[5];
    const float* W2   = (const float*)d_in[6];
    const float* b2   = (const float*)d_in[7];
    float* ws  = (float*)d_ws;
    float* out = (float*)d_out;

    k_big   <<<1296, 256, 0, stream>>>(adj, x, ws);
    k_mmA   <<<48,   256, 0, stream>>>(attL, ws);
    k_scores<<<256,  256, 0, stream>>>(x, ws);
    k_pv    <<<128,  192, 0, stream>>>(x, ws);
    k_mmB   <<<48,   256, 0, stream>>>(W1, ws);
    k_mmC   <<<48,   256, 0, stream>>>(attH, b1, ws);
    k_mmD   <<<48,   256, 0, stream>>>(W2, ws);
    k_final <<<1,    768, 0, stream>>>(b2, ws, out);
}

// Round 3
// 160.125 us; speedup vs baseline: 1.1611x; 1.0363x over previous
//
#include <hip/hip_runtime.h>

// ---------------- problem constants ----------------
constexpr int S    = 8192;
constexpr int D    = 768;
constexpr int NMID = 10;
constexpr int EPH  = 820;   // edges_per_high = ceil(8192/10)

// ---------------- workspace layout (float element offsets) ----------------
constexpr int PART_ADJ = 0;        // 3200   adjacency partials [pair][split32]
constexpr int PART_MID = 3200;     // 8*10*768 = 61440 mid partials [sp][cl][col]
constexpr int OFF_ZB   = 64640;    // zero-init base (4 atomic-target buffers)
constexpr int OFF_MATT = 64640;    // 7680  mid @ att_low_mid (atomic)
constexpr int OFF_Y1   = 72320;    // 7680  (mid+pv) @ W1 (atomic)
constexpr int OFF_Z2   = 80000;    // 3840  mid2 @ att_mid_high (atomic)
constexpr int OFF_Y2   = 83840;    // 3840  out2 @ W2 (atomic)
constexpr int ZERO_N   = 23040;    // ends at 87680
constexpr int OFF_MID  = 87680;    // 7680  reduced mid = m1^T x
constexpr int OFF_XMID = 95360;    // 7680
constexpr int OFF_SC   = 103040;   // 81920 raw masked scores [8192][10]
constexpr int OFF_SCB  = 184960;   // 256*10*2 per-block softmax stats
constexpr int OFF_PVP  = 190080;   // 64*10*768 PV partials [b][i][col]

// adjacency slicing: 100 pairs x 32 row-splits = 3200 items
__device__ __forceinline__ void adj_partial(const float* __restrict__ A,
                                            float* __restrict__ ws, int item) {
    __shared__ float wred[4];
    int p = item >> 5, s = item & 31;
    int i = p / 10, j = p % 10;
    int r0 = i * EPH, nr = min(EPH, S - r0);
    int c0 = j * EPH, nc = min(EPH, S - c0);
    int rs0 = r0 + (nr * s) / 32, rs1 = r0 + (nr * (s + 1)) / 32;
    int nc4 = nc >> 2;
    int tid = threadIdx.x;
    float acc = 0.f;
    for (int r = rs0; r < rs1; ++r) {
        const float4* row = (const float4*)(A + (size_t)r * S + c0);
        if (tid < nc4) {
            float4 v = row[tid];
            acc += (v.x + v.y) + (v.z + v.w);
        }
    }
#pragma unroll
    for (int off = 32; off > 0; off >>= 1) acc += __shfl_down(acc, off, 64);
    int ln = tid & 63, wv = tid >> 6;
    if (ln == 0) wred[wv] = acc;
    __syncthreads();
    if (tid == 0) ws[PART_ADJ + item] = (wred[0] + wred[1]) + (wred[2] + wred[3]);
}

// mid column-sum partials: 10 clusters x 3 col-chunks x 8 row-splits = 240 items
__device__ __forceinline__ void mid_partial(const float* __restrict__ x,
                                            float* __restrict__ ws, int item) {
    int cl = item / 24, rem = item % 24;
    int cc = rem >> 3, sp = rem & 7;
    int r0 = cl * EPH, nr = min(EPH, S - r0);
    int rs0 = r0 + (nr * sp) / 8, rs1 = r0 + (nr * (sp + 1)) / 8;
    int c = cc * 256 + threadIdx.x;
    float acc = 0.f;
    for (int r = rs0; r < rs1; ++r) acc += x[(size_t)r * D + c];
    ws[PART_MID + (sp * NMID + cl) * D + c] = acc;
}

// out[NR][768] += mi[NR][16] @ W[kb:kb+16][768]  (atomic, 48-way k-split)
template <int NR>
__device__ __forceinline__ void mm_core(const float* __restrict__ W,
                                        const float* mi,
                                        float* __restrict__ out, int kb) {
    int c = threadIdx.x;
    float a0[NR], a1[NR], a2[NR];
#pragma unroll
    for (int i = 0; i < NR; ++i) { a0[i] = 0.f; a1[i] = 0.f; a2[i] = 0.f; }
    for (int kk = 0; kk < 16; ++kk) {
        const float* wr = W + (size_t)(kb + kk) * D;
        float w0 = wr[c], w1 = wr[c + 256], w2 = wr[c + 512];
#pragma unroll
        for (int i = 0; i < NR; ++i) {
            float m = mi[i * 16 + kk];
            a0[i] += m * w0; a1[i] += m * w1; a2[i] += m * w2;
        }
    }
#pragma unroll
    for (int i = 0; i < NR; ++i) {
        atomicAdd(&out[i * D + c],       a0[i]);
        atomicAdd(&out[i * D + c + 256], a1[i]);
        atomicAdd(&out[i * D + c + 512], a2[i]);
    }
}

// ---- k1: adj items [0,800) + mid partials + zeroing ----
__global__ __launch_bounds__(256) void k1(const float* __restrict__ A,
                                          const float* __restrict__ x,
                                          float* __restrict__ ws) {
    int bx = blockIdx.x;
    if (bx < 800) adj_partial(A, ws, bx);
    else if (bx < 1040) mid_partial(x, ws, bx - 800);
    else {
        int b = bx - 1040;
        for (int t = b * 256 + threadIdx.x; t < ZERO_N; t += 16 * 256)
            ws[OFF_ZB + t] = 0.f;
    }
}

// ---- k2: mmA (reduce mid + mid@attL) + adj items [800,1600) ----
__global__ __launch_bounds__(256) void k2(const float* __restrict__ attL,
                                          const float* __restrict__ A,
                                          float* __restrict__ ws) {
    int bx = blockIdx.x;
    if (bx >= 48) { adj_partial(A, ws, 800 + bx - 48); return; }
    __shared__ float mi[160];
    int kb = bx * 16, tid = threadIdx.x;
    if (tid < 160) {
        int cl = tid >> 4, k = tid & 15;
        float s = 0.f;
#pragma unroll
        for (int sp = 0; sp < 8; ++sp)
            s += ws[PART_MID + (sp * NMID + cl) * D + kb + k];
        mi[tid] = s;
        ws[OFF_MID + cl * D + kb + k] = s;
    }
    __syncthreads();
    mm_core<10>(attL, mi, ws + OFF_MATT, kb);
}

// ---- k3: scores + stats (blocks 0..255) + adj items [1600,2200) ----
__global__ __launch_bounds__(256) void k3(const float* __restrict__ x,
                                          const float* __restrict__ A,
                                          float* __restrict__ ws) {
    int bx = blockIdx.x;
    if (bx >= 256) { adj_partial(A, ws, 1600 + bx - 256); return; }
    __shared__ float ma[NMID * D];   // 30 KB
    __shared__ float scl[32 * NMID];
    int tid = threadIdx.x;
    for (int t = tid; t < NMID * D; t += 256) ma[t] = ws[OFF_MATT + t];
    __syncthreads();
    const float4* maf = (const float4*)ma;
    const float4* x4  = (const float4*)x;
    int wave = tid >> 6, ln = tid & 63;
    int rbase = bx * 32 + wave * 8;
    for (int rr = 0; rr < 8; ++rr) {
        int r = rbase + rr;
        float4 v0 = x4[(size_t)r * 192 + ln];
        float4 v1 = x4[(size_t)r * 192 + 64 + ln];
        float4 v2 = x4[(size_t)r * 192 + 128 + ln];
        int rc = r / EPH;
#pragma unroll
        for (int i = 0; i < NMID; ++i) {
            float4 m0 = maf[i * 192 + ln];
            float4 m1 = maf[i * 192 + 64 + ln];
            float4 m2 = maf[i * 192 + 128 + ln];
            float p = m0.x * v0.x + m0.y * v0.y + m0.z * v0.z + m0.w * v0.w
                    + m1.x * v1.x + m1.y * v1.y + m1.z * v1.z + m1.w * v1.w
                    + m2.x * v2.x + m2.y * v2.y + m2.z * v2.z + m2.w * v2.w;
#pragma unroll
            for (int off = 32; off > 0; off >>= 1) p += __shfl_down(p, off, 64);
            if (ln == 0) {
                float v = (rc == i) ? 0.f : p;
                ws[OFF_SC + r * NMID + i] = v;
                scl[(wave * 8 + rr) * NMID + i] = v;
            }
        }
    }
    __syncthreads();
    if (tid < NMID) {
        float m = -1e30f;
        for (int r = 0; r < 32; ++r) m = fmaxf(m, scl[r * NMID + tid]);
        float s = 0.f;
        for (int r = 0; r < 32; ++r) s += expf(scl[r * NMID + tid] - m);
        ws[OFF_SCB + bx * 20 + tid * 2]     = m;
        ws[OFF_SCB + bx * 20 + tid * 2 + 1] = s;
    }
}

// ---- k4: softmax finalize + PV partials (blocks 0..63, 128 rows each)
//          + adj items [2200,2800) ----
__global__ __launch_bounds__(256) void k4(const float* __restrict__ x,
                                          const float* __restrict__ A,
                                          float* __restrict__ ws) {
    int bx = blockIdx.x;
    if (bx >= 64) { adj_partial(A, ws, 2200 + bx - 64); return; }
    __shared__ float lm[160], ls[160], Mi[10], Inv[10], p[128 * NMID];
    int tid = threadIdx.x;
    if (tid < 160) {
        int i = tid >> 4, seg = tid & 15;
        float m = -1e30f;
        for (int b = seg * 16; b < seg * 16 + 16; ++b)
            m = fmaxf(m, ws[OFF_SCB + b * 20 + i * 2]);
        float s = 0.f;
        for (int b = seg * 16; b < seg * 16 + 16; ++b)
            s += ws[OFF_SCB + b * 20 + i * 2 + 1] *
                 expf(ws[OFF_SCB + b * 20 + i * 2] - m);
        lm[tid] = m; ls[tid] = s;
    }
    __syncthreads();
    if (tid < NMID) {
        float M = -1e30f;
        for (int g = 0; g < 16; ++g) M = fmaxf(M, lm[tid * 16 + g]);
        float Ssum = 0.f;
        for (int g = 0; g < 16; ++g) Ssum += ls[tid * 16 + g] * expf(lm[tid * 16 + g] - M);
        Mi[tid] = M; Inv[tid] = 1.f / Ssum;
    }
    __syncthreads();
    int r0 = bx * 128;
    for (int t = tid; t < 128 * NMID; t += 256) {
        int i = t % NMID;
        p[t] = expf(ws[OFF_SC + r0 * NMID + t] - Mi[i]) * Inv[i];
    }
    __syncthreads();
    float a0[NMID], a1[NMID], a2[NMID];
#pragma unroll
    for (int i = 0; i < NMID; ++i) { a0[i] = 0.f; a1[i] = 0.f; a2[i] = 0.f; }
    for (int r = 0; r < 128; ++r) {
        const float* xr = x + (size_t)(r0 + r) * D;
        float x0 = xr[tid], x1 = xr[tid + 256], x2 = xr[tid + 512];
#pragma unroll
        for (int i = 0; i < NMID; ++i) {
            float pv = p[r * NMID + i];
            a0[i] += pv * x0; a1[i] += pv * x1; a2[i] += pv * x2;
        }
    }
#pragma unroll
    for (int i = 0; i < NMID; ++i) {
        float* base = ws + OFF_PVP + (bx * NMID + i) * D;
        base[tid]       = a0[i];
        base[tid + 256] = a1[i];
        base[tid + 512] = a2[i];
    }
}

// ---- k5: mmB ((mid + pv) @ W1) + adj items [2800,3200) ----
__global__ __launch_bounds__(256) void k5(const float* __restrict__ W1,
                                          const float* __restrict__ A,
                                          float* __restrict__ ws) {
    int bx = blockIdx.x;
    if (bx >= 48) { adj_partial(A, ws, 2800 + bx - 48); return; }
    __shared__ float mi[160];
    int kb = bx * 16, tid = threadIdx.x;
    if (tid < 160) {
        int cl = tid >> 4, k = tid & 15;
        float s = ws[OFF_MID + cl * D + kb + k];
        for (int b = 0; b < 64; ++b)
            s += ws[OFF_PVP + (b * NMID + cl) * D + kb + k];
        mi[tid] = s;
    }
    __syncthreads();
    mm_core<10>(W1, mi, ws + OFF_Y1, kb);
}

// ---- k6: NM; x_mid slice; mid2 @ attH -> Z2 ----
__global__ __launch_bounds__(256) void k6(const float* __restrict__ attH,
                                          const float* __restrict__ b1,
                                          float* __restrict__ ws) {
    __shared__ float aa[100], dg[10], NM[100], xml[160], mi[80];
    int tid = threadIdx.x;
    if (tid < 100) {
        float s = 0.f;
#pragma unroll
        for (int sp = 0; sp < 32; ++sp) s += ws[PART_ADJ + tid * 32 + sp];
        aa[tid] = s;
    }
    __syncthreads();
    if (tid < 10) {
        float s = 0.f;
#pragma unroll
        for (int j = 0; j < 10; ++j) s += (tid == j) ? 1.0f : aa[tid * 10 + j];
        dg[tid] = 1.0f / sqrtf(fmaxf(s, 1.0f));
    }
    __syncthreads();
    if (tid < 100) {
        int i = tid / 10, j = tid % 10;
        NM[tid] = dg[i] * ((i == j) ? 1.0f : aa[tid]) * dg[j];
    }
    __syncthreads();
    int kb = blockIdx.x * 16;
    if (tid < 160) {
        int i = tid >> 4, c = kb + (tid & 15);
        float s = b1[c];
#pragma unroll
        for (int j = 0; j < 10; ++j) s += NM[i * 10 + j] * ws[OFF_Y1 + j * D + c];
        float xm = fmaxf(s, 0.f);
        ws[OFF_XMID + i * D + c] = xm;
        xml[tid] = xm;
    }
    __syncthreads();
    if (tid < 80) {
        int a = tid >> 4, k = tid & 15;
        mi[tid] = xml[(2 * a) * 16 + k] + xml[(2 * a + 1) * 16 + k];
    }
    __syncthreads();
    mm_core<5>(attH, mi, ws + OFF_Z2, kb);
}

// ---- k7: level-2 attention + out2 @ W2 -> Y2 ----
__global__ __launch_bounds__(256) void k7(const float* __restrict__ W2,
                                          float* __restrict__ ws) {
    __shared__ float s2[64], P2[50], mi[80];
    int tid = threadIdx.x, wv = tid >> 6, ln = tid & 63;
    for (int pp = wv; pp < 50; pp += 4) {
        int i = pp / 10, r = pp % 10;
        const float4* za = (const float4*)(ws + OFF_Z2 + i * D);
        const float4* xa = (const float4*)(ws + OFF_XMID + r * D);
        float acc = 0.f;
#pragma unroll
        for (int q = 0; q < 3; ++q) {
            float4 a = za[q * 64 + ln], b = xa[q * 64 + ln];
            acc += a.x * b.x + a.y * b.y + a.z * b.z + a.w * b.w;
        }
#pragma unroll
        for (int off = 32; off > 0; off >>= 1) acc += __shfl_down(acc, off, 64);
        if (ln == 0) s2[pp] = ((r >> 1) == i) ? 0.f : acc;
    }
    __syncthreads();
    if (tid < 5) {
        float mx = -1e30f;
#pragma unroll
        for (int r = 0; r < 10; ++r) mx = fmaxf(mx, s2[tid * 10 + r]);
        float sm = 0.f; float e[10];
#pragma unroll
        for (int r = 0; r < 10; ++r) { e[r] = expf(s2[tid * 10 + r] - mx); sm += e[r]; }
#pragma unroll
        for (int r = 0; r < 10; ++r) P2[tid * 10 + r] = e[r] / sm;
    }
    __syncthreads();
    int kb = blockIdx.x * 16;
    if (tid < 80) {
        int i = tid >> 4, c = kb + (tid & 15);
        float xm[10];
#pragma unroll
        for (int r = 0; r < 10; ++r) xm[r] = ws[OFF_XMID + r * D + c];
        float o = xm[2 * i] + xm[2 * i + 1];
#pragma unroll
        for (int r = 0; r < 10; ++r) o += P2[i * 10 + r] * xm[r];
        mi[tid] = o;
    }
    __syncthreads();
    mm_core<5>(W2, mi, ws + OFF_Y2, kb);
}

// ---- k8: NH; out = mean relu(NH @ Y2 + b2) ----
__global__ __launch_bounds__(768) void k8(const float* __restrict__ b2,
                                          const float* __restrict__ ws,
                                          float* __restrict__ out) {
    __shared__ float aa[100], ha[25], dh[5], NH[25];
    int tid = threadIdx.x;
    if (tid < 100) {
        float s = 0.f;
#pragma unroll
        for (int sp = 0; sp < 32; ++sp) s += ws[PART_ADJ + tid * 32 + sp];
        aa[tid] = s;
    }
    __syncthreads();
    if (tid < 25) {
        int a = tid / 5, b = tid % 5;
        ha[tid] = aa[(2 * a) * 10 + 2 * b] + aa[(2 * a) * 10 + 2 * b + 1]
                + aa[(2 * a + 1) * 10 + 2 * b] + aa[(2 * a + 1) * 10 + 2 * b + 1];
    }
    __syncthreads();
    if (tid < 5) {
        float s = 0.f;
#pragma unroll
        for (int j = 0; j < 5; ++j) s += (tid == j) ? 1.0f : ha[tid * 5 + j];
        dh[tid] = 1.0f / sqrtf(fmaxf(s, 1.0f));
    }
    __syncthreads();
    if (tid < 25) {
        int i = tid / 5, j = tid % 5;
        NH[tid] = dh[i] * ((i == j) ? 1.0f : ha[tid]) * dh[j];
    }
    __syncthreads();
    int c = tid;
    float y[5];
#pragma unroll
    for (int j = 0; j < 5; ++j) y[j] = ws[OFF_Y2 + j * D + c];
    float bias = b2[c];
    float s = 0.f;
#pragma unroll
    for (int i = 0; i < 5; ++i) {
        float v = bias;
#pragma unroll
        for (int j = 0; j < 5; ++j) v += NH[i * 5 + j] * y[j];
        s += fmaxf(v, 0.f);
    }
    out[c] = s * 0.2f;
}

// ---------------- launcher ----------------
extern "C" void kernel_launch(void* const* d_in, const int* in_sizes, int n_in,
                              void* d_out, int out_size, void* d_ws, size_t ws_size,
                              hipStream_t stream) {
    const float* x    = (const float*)d_in[0];
    const float* adj  = (const float*)d_in[1];
    const float* attL = (const float*)d_in[2];
    const float* W1   = (const float*)d_in[3];
    const float* b1   = (const float*)d_in[4];
    const float* attH = (const float*)d_in[5];
    const float* W2   = (const float*)d_in[6];
    const float* b2   = (const float*)d_in[7];
    float* ws  = (float*)d_ws;
    float* out = (float*)d_out;

    k1<<<1056, 256, 0, stream>>>(adj, x, ws);
    k2<<<848,  256, 0, stream>>>(attL, adj, ws);
    k3<<<856,  256, 0, stream>>>(x, adj, ws);
    k4<<<664,  256, 0, stream>>>(x, adj, ws);
    k5<<<448,  256, 0, stream>>>(W1, adj, ws);
    k6<<<48,   256, 0, stream>>>(attH, b1, ws);
    k7<<<48,   256, 0, stream>>>(W2, ws);
    k8<<<1,    768, 0, stream>>>(b2, ws, out);
}